// Round 5
// baseline (176.944 us; speedup 1.0000x reference)
//
#include <hip/hip_runtime.h>
#include <hip/hip_bf16.h>

#define CCH 256
#define NPIX 4096
#define NB 8
#define LOG2E 1.4426950408889634f

typedef __attribute__((ext_vector_type(8))) short bf16x8;
typedef __attribute__((ext_vector_type(16))) float f32x16;

typedef __attribute__((address_space(3))) unsigned lds_u32;
typedef const __attribute__((address_space(1))) unsigned glb_u32;
#define GL_LDS16(gp, lp) \
    __builtin_amdgcn_global_load_lds((glb_u32*)(gp), (lds_u32*)(lp), 16, 0, 0)

static __device__ __forceinline__ unsigned pkbf(float a, float b) {
    union { __hip_bfloat16 h[2]; unsigned u; } p;
    p.h[0] = __float2bfloat16(a);
    p.h[1] = __float2bfloat16(b);
    return p.u;
}
static __device__ __forceinline__ unsigned short bf1(float a) {
    union { __hip_bfloat16 h; unsigned short s; } p;
    p.h = __float2bfloat16(a);
    return p.s;
}

// ---------------- Kernel 0: pack W fp32 -> bf16, Wb[320][256] ----------------
__global__ void packw_kernel(const float* __restrict__ Wq,
                             const float* __restrict__ Wk,
                             const float* __restrict__ Wv,
                             unsigned short* __restrict__ Wb) {
    int i4 = blockIdx.x * 256 + threadIdx.x;     // 20480 float4s total
    if (i4 >= 20480) return;
    int e = i4 * 4;
    const float* src;
    if (e < 8192)       src = Wq + e;
    else if (e < 16384) src = Wk + (e - 8192);
    else                src = Wv + (e - 16384);
    float4 v = *(const float4*)src;
    uint2 o;
    o.x = pkbf(v.x, v.y);
    o.y = pkbf(v.z, v.w);
    *(uint2*)(Wb + e) = o;
}

// ---------------- Kernel 1: QKV via MFMA ----------------
// x: [B,C,N] f32; Wb: [320][256] bf16 (rows: 32 q, 32 k, 256 v).
// Out: q [B][N][32] bf16 (prescaled by log2e), k [B][N][32],
//      v [B][C][N] with pixel column bit2<->bit3 swapped (PV B-frag order).
__global__ __launch_bounds__(320) void qkv_kernel(
    const float* __restrict__ x,
    const unsigned short* __restrict__ Wb,
    const float* __restrict__ bq, const float* __restrict__ bk,
    const float* __restrict__ bv,
    unsigned short* __restrict__ q, unsigned short* __restrict__ k,
    unsigned short* __restrict__ v)
{
    __shared__ __align__(16) unsigned xp[128][36];   // packed bf16 pairs (ch 2kp, 2kp+1)

    const int t   = threadIdx.x;
    const int b   = blockIdx.x >> 7;
    const int px0 = (blockIdx.x & 127) * 32;

    // stage x tile [256 ch][32 px] as bf16-pairs, coalesced float4 reads
    const float4* gx = (const float4*)x + ((size_t)b * CCH * NPIX + px0) / 4;
    for (int i = t; i < 1024; i += 320) {
        int kp = i >> 3, p4 = i & 7;
        float4 lo = gx[(size_t)(2 * kp) * (NPIX / 4) + p4];
        float4 hi = gx[(size_t)(2 * kp + 1) * (NPIX / 4) + p4];
        uint4 pk4;
        pk4.x = pkbf(lo.x, hi.x);
        pk4.y = pkbf(lo.y, hi.y);
        pk4.z = pkbf(lo.z, hi.z);
        pk4.w = pkbf(lo.w, hi.w);
        *(uint4*)&xp[kp][p4 * 4] = pk4;
    }
    __syncthreads();

    const int w  = t >> 6;            // wave 0..4: row-tiles {2w, 2w+1}
    const int lane = t & 63;
    const int qi = lane & 31, h = lane >> 5;

    f32x16 acc[2];
    #pragma unroll
    for (int rt = 0; rt < 2; ++rt)
        #pragma unroll
        for (int r = 0; r < 16; ++r) acc[rt][r] = 0.f;

    #pragma unroll 4
    for (int ks = 0; ks < 16; ++ks) {
        union { unsigned uw[4]; bf16x8 v8; } xb;
        #pragma unroll
        for (int j = 0; j < 4; ++j) xb.uw[j] = xp[ks * 8 + 4 * h + j][qi];
        #pragma unroll
        for (int rt = 0; rt < 2; ++rt) {
            int row = (2 * w + rt) * 32 + qi;
            bf16x8 af = *(const bf16x8*)(Wb + (size_t)row * 256 + ks * 16 + h * 8);
            acc[rt] = __builtin_amdgcn_mfma_f32_32x32x16_bf16(af, xb.v8, acc[rt], 0, 0, 0);
        }
    }

    const int px = px0 + qi;                                   // q/k pixel
    const int pxv = px0 + ((qi & 19) | ((qi & 4) << 1) | ((qi & 8) >> 1)); // v: bits 2<->3
    #pragma unroll
    for (int rt = 0; rt < 2; ++rt) {
        int tile = 2 * w + rt;
        if (tile < 2) {                // q or k rows
            const float* bias = (tile == 0) ? bq : bk;
            unsigned short* outp = (tile == 0) ? q : k;
            float scale = (tile == 0) ? LOG2E : 1.0f;
            #pragma unroll
            for (int rg = 0; rg < 4; ++rg) {
                float vv[4];
                #pragma unroll
                for (int j = 0; j < 4; ++j) {
                    int outd = j + 8 * rg + 4 * h;
                    vv[j] = (acc[rt][4 * rg + j] + bias[outd]) * scale;
                }
                uint2 st;
                st.x = pkbf(vv[0], vv[1]);
                st.y = pkbf(vv[2], vv[3]);
                *(uint2*)(outp + ((size_t)b * NPIX + px) * 32 + 8 * rg + 4 * h) = st;
            }
        } else {                       // v rows, d-major out, permuted pixel col
            #pragma unroll
            for (int r = 0; r < 16; ++r) {
                int outd = (r & 3) + 8 * (r >> 2) + 4 * h;
                int grow = (tile - 2) * 32 + outd;
                v[((size_t)b * CCH + grow) * NPIX + pxv] = bf1(acc[rt][r] + bv[grow]);
            }
        }
    }
}

// ---------------- Kernel 2: MFMA flash attention, dbuf + global_load_lds -----
// P B-frags are each lane's own sacc registers (V key axis pre-permuted).
// LDS slot layout identical to r4; swizzle applied on the GLOBAL source so the
// linear global_load_lds dest still yields the same read-side swizzle.
__global__ __launch_bounds__(256, 2) void attn_kernel(
    const unsigned short* __restrict__ qg,
    const unsigned short* __restrict__ kg,
    const unsigned short* __restrict__ vg,
    const float* __restrict__ x,
    const float* __restrict__ gamma,
    float* __restrict__ out)
{
    __shared__ __align__(16) unsigned short Kl[2][64][4][8];    // 8 KB
    __shared__ __align__(16) unsigned short Vl[2][256][8][8];   // 64 KB

    const int t    = threadIdx.x;
    const int b    = blockIdx.x & 7;          // batch == XCD -> K/V L2-resident
    const int n0   = (blockIdx.x >> 3) * 64;
    const int w    = t >> 6;
    const int lane = t & 63;
    const int qtile = w >> 1, chalf = w & 1;
    const int qi = lane & 31, h = lane >> 5;

    bf16x8 qf[2];
    {
        const unsigned short* qp = qg + ((size_t)b * NPIX + n0 + qtile * 32 + qi) * 32;
        qf[0] = *(const bf16x8*)(qp + h * 8);
        qf[1] = *(const bf16x8*)(qp + 16 + h * 8);
    }

    f32x16 acc[4];
    #pragma unroll
    for (int ct = 0; ct < 4; ++ct)
        #pragma unroll
        for (int r = 0; r < 16; ++r) acc[ct][r] = 0.f;
    float l_run = 0.f;

    // staging identities (swizzle on the global source; LDS dest is linear)
    const int kk_key = t >> 2, kk_sc = t & 3;
    const int kswz   = kk_sc ^ (kk_key & 3);
    const int vk_g   = t >> 3, vk_kc = t & 7;
    const int vswz   = vk_kc ^ (vk_g & 7);

    const unsigned short* kg_base = kg + ((size_t)b * NPIX + kk_key) * 32 + kswz * 8;
    const unsigned short* vg_base = vg + ((size_t)b * CCH + vk_g) * NPIX + vswz * 8;
    char* kl0 = (char*)&Kl[0][0][0][0] + w * 1024;   // wave-uniform LDS bases
    char* vl0 = (char*)&Vl[0][0][0][0] + w * 1024;

    auto stage = [&](int bb, int kt1) {
        const int k0 = kt1 * 64;
        GL_LDS16(kg_base + (size_t)k0 * 32, kl0 + bb * 4096);
        const unsigned short* vp = vg_base + k0;
        char* vl = vl0 + bb * 32768;
        #pragma unroll
        for (int p = 0; p < 8; ++p)
            GL_LDS16(vp + (size_t)p * 32 * NPIX, vl + p * 4096);
    };

    stage(0, 0);
    __syncthreads();

    for (int kt = 0; kt < NPIX / 64; ++kt) {
        const int cur = kt & 1;
        if (kt < NPIX / 64 - 1) stage(cur ^ 1, kt + 1);   // prefetch next tile

        // S^T[key][query] = K · Q^T
        f32x16 sacc[2];
        #pragma unroll
        for (int sub = 0; sub < 2; ++sub) {
            #pragma unroll
            for (int r = 0; r < 16; ++r) sacc[sub][r] = 0.f;
            #pragma unroll
            for (int s = 0; s < 2; ++s) {
                bf16x8 kf = *(const bf16x8*)&Kl[cur][sub * 32 + qi][(2 * s + h) ^ (qi & 3)][0];
                sacc[sub] = __builtin_amdgcn_mfma_f32_32x32x16_bf16(kf, qf[s], sacc[sub], 0, 0, 0);
            }
        }

        // softmax weights -> B-frags: lane's own 8 consecutive sacc regs, in order
        bf16x8 pf[4];
        #pragma unroll
        for (int sub = 0; sub < 2; ++sub) {
            #pragma unroll
            for (int sp = 0; sp < 2; ++sp) {
                union { unsigned uw[4]; bf16x8 v8; } pk;
                float ps = 0.f;
                #pragma unroll
                for (int c = 0; c < 4; ++c) {
                    float ea = exp2f(sacc[sub][8 * sp + 2 * c]);
                    float eb = exp2f(sacc[sub][8 * sp + 2 * c + 1]);
                    ps += ea + eb;
                    pk.uw[c] = pkbf(ea, eb);
                }
                l_run += ps;
                pf[2 * sub + sp] = pk.v8;
            }
        }

        // O^T += V^T · P^T
        __builtin_amdgcn_s_setprio(1);
        #pragma unroll
        for (int ct = 0; ct < 4; ++ct) {
            const int c = chalf * 128 + ct * 32 + qi;
            #pragma unroll
            for (int s = 0; s < 4; ++s) {
                bf16x8 vf = *(const bf16x8*)&Vl[cur][c][(2 * s + h) ^ (qi & 7)][0];
                acc[ct] = __builtin_amdgcn_mfma_f32_32x32x16_bf16(vf, pf[s], acc[ct], 0, 0, 0);
            }
        }
        __builtin_amdgcn_s_setprio(0);

        __syncthreads();   // drains vmcnt(0): next tile's LDS writes landed
    }

    float l = l_run + __shfl_xor(l_run, 32, 64);
    const float rs = gamma[0] / l;
    #pragma unroll
    for (int ct = 0; ct < 4; ++ct) {
        #pragma unroll
        for (int r = 0; r < 16; ++r) {
            int c = chalf * 128 + ct * 32 + (r & 3) + 8 * (r >> 2) + 4 * h;
            size_t off = ((size_t)b * CCH + c) * NPIX + n0 + qtile * 32 + qi;
            out[off] = rs * acc[ct][r] + x[off];
        }
    }
}

extern "C" void kernel_launch(void* const* d_in, const int* in_sizes, int n_in,
                              void* d_out, int out_size, void* d_ws, size_t ws_size,
                              hipStream_t stream) {
    const float* x     = (const float*)d_in[0];
    const float* Wq    = (const float*)d_in[1];
    const float* bq    = (const float*)d_in[2];
    const float* Wk    = (const float*)d_in[3];
    const float* bk    = (const float*)d_in[4];
    const float* Wv    = (const float*)d_in[5];
    const float* bv    = (const float*)d_in[6];
    const float* gamma = (const float*)d_in[7];
    float* out = (float*)d_out;

    // ws: Wb(320*256) | q | k | v   (bf16, ~20.3 MB)
    unsigned short* Wb = (unsigned short*)d_ws;
    unsigned short* qw = Wb + 320 * 256;
    unsigned short* kw = qw + (size_t)NB * NPIX * 32;
    unsigned short* vw = kw + (size_t)NB * NPIX * 32;

    packw_kernel<<<dim3(80), dim3(256), 0, stream>>>(Wq, Wk, Wv, Wb);
    qkv_kernel<<<dim3(NB * (NPIX / 32)), dim3(320), 0, stream>>>(
        x, Wb, bq, bk, bv, qw, kw, vw);
    attn_kernel<<<dim3(NB * (NPIX / 64)), dim3(256), 0, stream>>>(
        qw, kw, vw, x, gamma, out);
}